// Round 6
// baseline (152.527 us; speedup 1.0000x reference)
//
#include <hip/hip_runtime.h>

// Problem constants (from reference): x (2,14,128,256,96) f32, wid (2,128,256) int
namespace {
constexpr int kB   = 2;
constexpr int kPl  = 14;
constexpr int kLat = 128;
constexpr int kLon = 256;
constexpr int kC   = 96;
constexpr int kNumDirs = 9;
constexpr int kC4  = kC / 4;                         // 24 float4 per row
constexpr int kNTotal = kB * kPl * kLat * kLon * kC; // 88,080,384
constexpr int kN4 = kNTotal / 4;                     // 22,020,096 = 2^20 * 21
constexpr int kRegions = kB * 4 * 8;                 // 64
constexpr int kCopyBlocks = 2048;                    // 2^19 threads
constexpr int kPerThread  = kN4 / (kCopyBlocks * 256); // 42
}

typedef float f4 __attribute__((ext_vector_type(4)));

// WIND_DIRS lat/lon shifts (scale 2 applied in packing):
// dir: 0:(0,0) 1:(-1,0) 2:(-1,1) 3:(0,1) 4:(1,1) 5:(1,0) 6:(1,-1) 7:(0,-1) 8:(-1,-1)
__device__ __constant__ int c_lat_s[kNumDirs] = {0,-1,-1, 0, 1, 1, 1, 0,-1};
__device__ __constant__ int c_lon_s[kNumDirs] = {0, 0, 1, 1, 1, 0,-1,-1,-1};

// One block per (b, rlat, rlon) 32x32 region.
__global__ __launch_bounds__(256) void region_dirs_kernel(
        const int* __restrict__ wid, int* __restrict__ rdpack,
        int* __restrict__ cnt_blk) {
    __shared__ int cnt[kNumDirs];
    const int t = threadIdx.x;
    if (t < kNumDirs) cnt[t] = 0;
    __syncthreads();

    const int blk  = blockIdx.x;        // 0..63
    const int rlon = blk & 7;
    const int rlat = (blk >> 3) & 3;
    const int b    = blk >> 5;

    for (int k = t; k < 1024; k += 256) {
        const int i  = k >> 5;
        const int j  = k & 31;
        const int la = rlat * 32 + i;
        const int lo = rlon * 32 + j;
        atomicAdd(&cnt[wid[(b * kLat + la) * kLon + lo]], 1);
    }
    __syncthreads();

    if (t < kNumDirs) cnt_blk[blk * kNumDirs + t] = cnt[t];
    if (t == 0) {
        int best = 0, bestc = cnt[0];
        #pragma unroll
        for (int d = 1; d < kNumDirs; ++d)
            if (cnt[d] > bestc) { bestc = cnt[d]; best = d; }  // first-max tie
        const int dla = 3 - 2 * c_lat_s[best];   // {1,3,5}
        const int dlo = 6 - 2 * c_lon_s[best];   // {4,6,8}
        rdpack[blk] = (dla << 8) | dlo;
    }
}

// Pure gather permutation: out[b,p,la,lo,c] = x[b,(p+1)%14,(la+dla)&127,(lo+dlo)&255,c]
// rdpack table lives in LDS: region lookup is an lgkm ds_read with no L1/L2
// dependence, so the only VMEM on the address critical path is the x load.
__global__ __launch_bounds__(256) void gather_kernel(
        const f4* __restrict__ x, const int* __restrict__ rdpack,
        const int* __restrict__ cnt_blk, f4* __restrict__ out,
        float* __restrict__ out_dom) {
    if (blockIdx.x == kCopyBlocks) {
        // global dominant direction: sum 64 region histograms, first-max argmax
        __shared__ int tot[kNumDirs];
        const int t = threadIdx.x;
        if (t < kNumDirs) {
            int s = 0;
            for (int r = 0; r < kRegions; ++r) s += cnt_blk[r * kNumDirs + t];
            tot[t] = s;
        }
        __syncthreads();
        if (t == 0) {
            int best = 0, bestc = tot[0];
            #pragma unroll
            for (int d = 1; d < kNumDirs; ++d)
                if (tot[d] > bestc) { bestc = tot[d]; best = d; }
            *out_dom = (float)best;
        }
        return;
    }

    __shared__ int s_pack[kRegions];
    if (threadIdx.x < kRegions) s_pack[threadIdx.x] = rdpack[threadIdx.x];
    __syncthreads();

    const int base = blockIdx.x * 256 + threadIdx.x;   // 0 .. 2^19-1
    constexpr int kStride = kCopyBlocks * 256;         // 2^19

    #pragma unroll 6
    for (int k = 0; k < kPerThread; ++k) {
        const int i = base + k * kStride;
        const int c4 = i % kC4;
        int r = i / kC4;
        const int lo = r & (kLon - 1); r >>= 8;
        const int la = r & (kLat - 1); r >>= 7;
        const int p  = r % kPl;
        const int b  = r / kPl;

        const int pack = s_pack[(b * 4 + (la >> 5)) * 8 + (lo >> 5)];
        const int lasrc = (la + (pack >> 8)) & (kLat - 1);
        const int losrc = (lo + (pack & 0xff)) & (kLon - 1);
        int psrc = p + 1; if (psrc >= kPl) psrc = 0;

        const int src = (((b * kPl + psrc) * kLat + lasrc) * kLon + losrc) * kC4 + c4;
        const f4 v = x[src];
        __builtin_nontemporal_store(v, &out[i]);
    }
}

extern "C" void kernel_launch(void* const* d_in, const int* in_sizes, int n_in,
                              void* d_out, int out_size, void* d_ws, size_t ws_size,
                              hipStream_t stream) {
    const float* x   = (const float*)d_in[0];
    const int*   wid = (const int*)d_in[1];
    float* out = (float*)d_out;

    // ws layout: [0..63] rdpack, [64..64+576) per-block counts
    int* rdpack  = (int*)d_ws;
    int* cnt_blk = rdpack + kRegions;

    region_dirs_kernel<<<kRegions, 256, 0, stream>>>(wid, rdpack, cnt_blk);
    gather_kernel<<<kCopyBlocks + 1, 256, 0, stream>>>(
        (const f4*)x, rdpack, cnt_blk, (f4*)out, out + kNTotal);
}

// Round 7
// 133.866 us; speedup vs baseline: 1.1394x; 1.1394x over previous
//
#include <hip/hip_runtime.h>

// Problem constants (from reference): x (2,14,128,256,96) f32, wid (2,128,256) int
namespace {
constexpr int kB   = 2;
constexpr int kPl  = 14;
constexpr int kLat = 128;
constexpr int kLon = 256;
constexpr int kC   = 96;
constexpr int kNumDirs = 9;
constexpr int kC4  = kC / 4;                         // 24 float4 per row
constexpr int kNTotal = kB * kPl * kLat * kLon * kC; // 88,080,384
constexpr int kRegions = kB * 4 * 8;                 // 64
constexpr int kRowTasks = kB * kPl * kLat;           // 3584 (one output lat-row each)
constexpr int kRowF4 = kLon * kC4;                   // 6144 f4 = 96 KB per row
constexpr int kRowIters = kRowF4 / 256;              // 24 per thread
}

typedef float f4 __attribute__((ext_vector_type(4)));

// WIND_DIRS lat/lon shifts (scale 2 applied in packing):
// dir: 0:(0,0) 1:(-1,0) 2:(-1,1) 3:(0,1) 4:(1,1) 5:(1,0) 6:(1,-1) 7:(0,-1) 8:(-1,-1)
__device__ __constant__ int c_lat_s[kNumDirs] = {0,-1,-1, 0, 1, 1, 1, 0,-1};
__device__ __constant__ int c_lon_s[kNumDirs] = {0, 0, 1, 1, 1, 0,-1,-1,-1};

// One block per (b, rlat, rlon) 32x32 region.
__global__ __launch_bounds__(256) void region_dirs_kernel(
        const int* __restrict__ wid, int* __restrict__ rdpack,
        int* __restrict__ cnt_blk) {
    __shared__ int cnt[kNumDirs];
    const int t = threadIdx.x;
    if (t < kNumDirs) cnt[t] = 0;
    __syncthreads();

    const int blk  = blockIdx.x;        // 0..63
    const int rlon = blk & 7;
    const int rlat = (blk >> 3) & 3;
    const int b    = blk >> 5;

    for (int k = t; k < 1024; k += 256) {
        const int i  = k >> 5;
        const int j  = k & 31;
        const int la = rlat * 32 + i;
        const int lo = rlon * 32 + j;
        atomicAdd(&cnt[wid[(b * kLat + la) * kLon + lo]], 1);
    }
    __syncthreads();

    if (t < kNumDirs) cnt_blk[blk * kNumDirs + t] = cnt[t];
    if (t == 0) {
        int best = 0, bestc = cnt[0];
        #pragma unroll
        for (int d = 1; d < kNumDirs; ++d)
            if (cnt[d] > bestc) { bestc = cnt[d]; best = d; }  // first-max tie
        const int dla = 3 - 2 * c_lat_s[best];   // {1,3,5}
        const int dlo = 6 - 2 * c_lon_s[best];   // {4,6,8}
        rdpack[blk] = (dla << 8) | dlo;
    }
}

// One block per output lat-row (b,p,la): writes 96 KB sequentially, reads 8
// contiguous ~12 KB source segments (one per lon-region). Maximizes DRAM page
// locality per stream vs 1 KB grid-stride interleave.
__global__ __launch_bounds__(256) void gather_rows_kernel(
        const f4* __restrict__ x, const int* __restrict__ rdpack,
        const int* __restrict__ cnt_blk, f4* __restrict__ out,
        float* __restrict__ out_dom) {
    if (blockIdx.x == kRowTasks) {
        // global dominant direction: sum 64 region histograms, first-max argmax
        __shared__ int tot[kNumDirs];
        const int t = threadIdx.x;
        if (t < kNumDirs) {
            int s = 0;
            for (int r = 0; r < kRegions; ++r) s += cnt_blk[r * kNumDirs + t];
            tot[t] = s;
        }
        __syncthreads();
        if (t == 0) {
            int best = 0, bestc = tot[0];
            #pragma unroll
            for (int d = 1; d < kNumDirs; ++d)
                if (tot[d] > bestc) { bestc = tot[d]; best = d; }
            *out_dom = (float)best;
        }
        return;
    }

    const int t   = threadIdx.x;
    const int blk = blockIdx.x;            // task = (b*kPl + p)*kLat + la
    const int la  = blk & (kLat - 1);
    const int bp  = blk >> 7;
    const int p   = bp % kPl;
    const int b   = bp / kPl;
    int psrc = p + 1; if (psrc >= kPl) psrc = 0;

    // 8-entry pack row for this (b, la-region): block-uniform
    __shared__ int s_pack8[8];
    if (t < 8) s_pack8[t] = rdpack[(b * 4 + (la >> 5)) * 8 + t];
    __syncthreads();

    const long srow = (long)((b * kPl + psrc) * kLat) * kRowF4; // base of source (b,psrc) plane
    const long drow = (long)blk * kRowF4;                       // this output row

    #pragma unroll 6
    for (int k = 0; k < kRowIters; ++k) {
        const int flat = k * 256 + t;        // 0..6143, block-sequential
        const int lo   = flat / kC4;
        const int c4   = flat - lo * kC4;

        const int pack  = s_pack8[lo >> 5];
        const int lasrc = (la + (pack >> 8)) & (kLat - 1);
        const int losrc = (lo + (pack & 0xff)) & (kLon - 1);

        const long src = srow + (long)lasrc * kRowF4 + losrc * kC4 + c4;
        const f4 v = __builtin_nontemporal_load(&x[src]);
        __builtin_nontemporal_store(v, &out[drow + flat]);
    }
}

extern "C" void kernel_launch(void* const* d_in, const int* in_sizes, int n_in,
                              void* d_out, int out_size, void* d_ws, size_t ws_size,
                              hipStream_t stream) {
    const float* x   = (const float*)d_in[0];
    const int*   wid = (const int*)d_in[1];
    float* out = (float*)d_out;

    // ws layout: [0..63] rdpack, [64..64+576) per-block counts
    int* rdpack  = (int*)d_ws;
    int* cnt_blk = rdpack + kRegions;

    region_dirs_kernel<<<kRegions, 256, 0, stream>>>(wid, rdpack, cnt_blk);
    gather_rows_kernel<<<kRowTasks + 1, 256, 0, stream>>>(
        (const f4*)x, rdpack, cnt_blk, (f4*)out, out + kNTotal);
}

// Round 8
// 130.353 us; speedup vs baseline: 1.1701x; 1.0270x over previous
//
#include <hip/hip_runtime.h>

// Problem constants (from reference): x (2,14,128,256,96) f32, wid (2,128,256) int
namespace {
constexpr int kB   = 2;
constexpr int kPl  = 14;
constexpr int kLat = 128;
constexpr int kLon = 256;
constexpr int kC   = 96;
constexpr int kNumDirs = 9;
constexpr int kC4  = kC / 4;                         // 24 float4 per row
constexpr int kNTotal = kB * kPl * kLat * kLon * kC; // 88,080,384
constexpr int kRegions = kB * 4 * 8;                 // 64
constexpr int kRowTasks = kB * kPl * kLat;           // 3584 (one output lat-row each)
constexpr int kRowF4 = kLon * kC4;                   // 6144 f4 = 96 KB per row
constexpr int kRowIters = kRowF4 / 256;              // 24 per thread
}

typedef float f4 __attribute__((ext_vector_type(4)));

// WIND_DIRS lat/lon shifts (scale 2 applied in packing):
// dir: 0:(0,0) 1:(-1,0) 2:(-1,1) 3:(0,1) 4:(1,1) 5:(1,0) 6:(1,-1) 7:(0,-1) 8:(-1,-1)
__device__ __constant__ int c_lat_s[kNumDirs] = {0,-1,-1, 0, 1, 1, 1, 0,-1};
__device__ __constant__ int c_lon_s[kNumDirs] = {0, 0, 1, 1, 1, 0,-1,-1,-1};

// One block per (b, rlat, rlon) 32x32 region.
__global__ __launch_bounds__(256) void region_dirs_kernel(
        const int* __restrict__ wid, int* __restrict__ rdpack,
        int* __restrict__ cnt_blk) {
    __shared__ int cnt[kNumDirs];
    const int t = threadIdx.x;
    if (t < kNumDirs) cnt[t] = 0;
    __syncthreads();

    const int blk  = blockIdx.x;        // 0..63
    const int rlon = blk & 7;
    const int rlat = (blk >> 3) & 3;
    const int b    = blk >> 5;

    for (int k = t; k < 1024; k += 256) {
        const int i  = k >> 5;
        const int j  = k & 31;
        const int la = rlat * 32 + i;
        const int lo = rlon * 32 + j;
        atomicAdd(&cnt[wid[(b * kLat + la) * kLon + lo]], 1);
    }
    __syncthreads();

    if (t < kNumDirs) cnt_blk[blk * kNumDirs + t] = cnt[t];
    if (t == 0) {
        int best = 0, bestc = cnt[0];
        #pragma unroll
        for (int d = 1; d < kNumDirs; ++d)
            if (cnt[d] > bestc) { bestc = cnt[d]; best = d; }  // first-max tie
        const int dla = 3 - 2 * c_lat_s[best];   // {1,3,5}
        const int dlo = 6 - 2 * c_lon_s[best];   // {4,6,8}
        rdpack[blk] = (dla << 8) | dlo;
    }
}

// One block per output lat-row (b,p,la): writes 96 KB sequentially, reads 8
// contiguous ~12 KB source segments (one per lon-region).
// Loads are PLAIN (retain x in L3 across replays); stores are NONTEMPORAL
// (out is never read — don't let it evict x from L3).
__global__ __launch_bounds__(256) void gather_rows_kernel(
        const f4* __restrict__ x, const int* __restrict__ rdpack,
        const int* __restrict__ cnt_blk, f4* __restrict__ out,
        float* __restrict__ out_dom) {
    if (blockIdx.x == kRowTasks) {
        // global dominant direction: sum 64 region histograms, first-max argmax
        __shared__ int tot[kNumDirs];
        const int t = threadIdx.x;
        if (t < kNumDirs) {
            int s = 0;
            for (int r = 0; r < kRegions; ++r) s += cnt_blk[r * kNumDirs + t];
            tot[t] = s;
        }
        __syncthreads();
        if (t == 0) {
            int best = 0, bestc = tot[0];
            #pragma unroll
            for (int d = 1; d < kNumDirs; ++d)
                if (tot[d] > bestc) { bestc = tot[d]; best = d; }
            *out_dom = (float)best;
        }
        return;
    }

    const int t   = threadIdx.x;
    const int blk = blockIdx.x;            // task = (b*kPl + p)*kLat + la
    const int la  = blk & (kLat - 1);
    const int bp  = blk >> 7;
    const int p   = bp % kPl;
    const int b   = bp / kPl;
    int psrc = p + 1; if (psrc >= kPl) psrc = 0;

    // 8-entry pack row for this (b, la-region): block-uniform
    __shared__ int s_pack8[8];
    if (t < 8) s_pack8[t] = rdpack[(b * 4 + (la >> 5)) * 8 + t];
    __syncthreads();

    const long srow = (long)((b * kPl + psrc) * kLat) * kRowF4; // source (b,psrc) plane base
    const long drow = (long)blk * kRowF4;                       // this output row

    #pragma unroll 6
    for (int k = 0; k < kRowIters; ++k) {
        const int flat = k * 256 + t;        // 0..6143, block-sequential
        const int lo   = flat / kC4;
        const int c4   = flat - lo * kC4;

        const int pack  = s_pack8[lo >> 5];
        const int lasrc = (la + (pack >> 8)) & (kLat - 1);
        const int losrc = (lo + (pack & 0xff)) & (kLon - 1);

        const long src = srow + (long)lasrc * kRowF4 + losrc * kC4 + c4;
        const f4 v = x[src];                              // plain load: keep in L3
        __builtin_nontemporal_store(v, &out[drow + flat]); // nt store: don't cache out
    }
}

extern "C" void kernel_launch(void* const* d_in, const int* in_sizes, int n_in,
                              void* d_out, int out_size, void* d_ws, size_t ws_size,
                              hipStream_t stream) {
    const float* x   = (const float*)d_in[0];
    const int*   wid = (const int*)d_in[1];
    float* out = (float*)d_out;

    // ws layout: [0..63] rdpack, [64..64+576) per-block counts
    int* rdpack  = (int*)d_ws;
    int* cnt_blk = rdpack + kRegions;

    region_dirs_kernel<<<kRegions, 256, 0, stream>>>(wid, rdpack, cnt_blk);
    gather_rows_kernel<<<kRowTasks + 1, 256, 0, stream>>>(
        (const f4*)x, rdpack, cnt_blk, (f4*)out, out + kNTotal);
}